// Round 12
// baseline (28.612 us; speedup 1.0000x reference)
//
#include <hip/hip_runtime.h>
#include <hip/hip_cooperative_groups.h>
#include <math.h>

namespace cg = cooperative_groups;

#define LL 1024
#define BB 1024
#define NCHUNK4 256
#define SEGS 8
#define STEPS 32           // chunk4 steps per segment
#define RST 20             // LDS row stride (floats): 2-way banks, f4-aligned
#define SLOT20 328         // LDS matrix slot stride (floats)

typedef float f32x4 __attribute__((ext_vector_type(4)));
typedef short s16x8 __attribute__((ext_vector_type(8)));

#define FMA4(acc, s, v) { (acc).x += (s)*(v).x; (acc).y += (s)*(v).y; \
                          (acc).z += (s)*(v).z; (acc).w += (s)*(v).w; }

__device__ inline unsigned f2bf(float f) {   // RNE f32->bf16 bits
    unsigned u = __float_as_uint(f);
    return (u + 0x7FFFu + ((u >> 16) & 1u)) >> 16;
}

// ---------------------------------------------------------------------------
// 16x16 fp32 matmul in stride-20 LDS, 64 threads per product (verified R10).
// ---------------------------------------------------------------------------
__device__ inline void mulRST(float* L, int sx, int sy, int sd, int sub) {
    const int q = sub >> 4, j = sub & 15;
    const float* X = &L[sx*SLOT20 + j*RST];
    const float* Y = &L[sy*SLOT20 + 4*q];
    float4 o = make_float4(0.f, 0.f, 0.f, 0.f);
    #pragma unroll
    for (int i = 0; i < 16; ++i) {
        const float a = X[i];
        const float4 y = *reinterpret_cast<const float4*>(Y + i*RST);
        FMA4(o, a, y);
    }
    *reinterpret_cast<float4*>(&L[sd*SLOT20 + j*RST + 4*q]) = o;
}

// ---------------------------------------------------------------------------
// Build phase body (verified R10/R11 math). Block build-id bid handles
// (c = bid>>2, m01 = bid&3); all __syncthreads at full-block scope.
// ---------------------------------------------------------------------------
__device__ inline void build_phase(float* L, const float* __restrict__ km,
                                   uint2* __restrict__ TA, int bid, int tt) {
    const int c   = bid >> 2;
    const int m01 = bid & 3;
    const int xs0 = m01 >> 1, xs1 = m01 & 1;
    // slots: 0=M0 1=M1 2=M2a 3=M2b 4=M3a 5=M3b 6=P 7=Q0 8=Q1 9..12=T0..T3
    if (tt < 256) {
        const int dst = (tt >> 4)*RST + (tt & 15);
        L[0*SLOT20 + dst] = km[((4*c + 0)*2 + xs0)*256 + tt];
        L[1*SLOT20 + dst] = km[((4*c + 1)*2 + xs1)*256 + tt];
        L[2*SLOT20 + dst] = km[((4*c + 2)*2 + 0)*256 + tt];
        L[3*SLOT20 + dst] = km[((4*c + 2)*2 + 1)*256 + tt];
        L[4*SLOT20 + dst] = km[((4*c + 3)*2 + 0)*256 + tt];
        L[5*SLOT20 + dst] = km[((4*c + 3)*2 + 1)*256 + tt];
    }
    __syncthreads();
    const int w = tt >> 6, sub = tt & 63;
    if (w == 0) mulRST(L, 0, 1, 6, sub);                        // P = M0@M1
    __syncthreads();
    if (w < 2) mulRST(L, 6, 2 + w, 7 + w, sub);                 // Qw = P@M2[w]
    __syncthreads();
    if (w < 4) mulRST(L, 7 + (w >> 1), 4 + (w & 1), 9 + w, sub);// Tw
    __syncthreads();
    if (tt < 256) {   // emit combo qq = w, lane = sub
        const int g = sub >> 4, col = sub & 15;
        const float* Tq = &L[(9 + w) * SLOT20];
        const unsigned a0 = f2bf(Tq[(4*g+0)*RST + col]);
        const unsigned a1 = f2bf(Tq[(4*g+1)*RST + col]);
        const unsigned a2 = f2bf(Tq[(4*g+2)*RST + col]);
        const unsigned a3 = f2bf(Tq[(4*g+3)*RST + col]);
        TA[((size_t)c*16 + m01*4 + w)*64 + sub] =
            make_uint2(a0 | (a1 << 16), a2 | (a3 << 16));
    }
}

// ---------------------------------------------------------------------------
// Chain+combine phase body (verified R11 math, bit-identical output).
// ---------------------------------------------------------------------------
__device__ inline void chain_phase(float* mats, const uint2* __restrict__ TA,
                                   const int* __restrict__ x,
                                   float* __restrict__ out, int b, int tt) {
    const int s    = tt >> 6;          // wave = segment
    const int lane = tt & 63;
    const int g = lane >> 4, c = lane & 15;

    int mv = 0;
    {
        const int4* xp4 = reinterpret_cast<const int4*>(x + (size_t)b*LL + s*(STEPS*4));
        if (lane < STEPS) {
            const int4 xv = xp4[lane];
            mv = (xv.x<<3) | (xv.y<<2) | (xv.z<<1) | xv.w;
        }
    }
    const uint2* __restrict__ TAs = TA + (size_t)s*STEPS*16*64;

    const f32x4 zero = {0.f, 0.f, 0.f, 0.f};
    f32x4 d = zero;
    unsigned h01 = ((4*g+0==c)?0x3F80u:0u) | (((4*g+1==c)?0x3F80u:0u) << 16);
    unsigned h23 = ((4*g+2==c)?0x3F80u:0u) | (((4*g+3==c)?0x3F80u:0u) << 16);
    unsigned l01 = 0u, l23 = 0u;

    #pragma unroll
    for (int t = 0; t < STEPS; ++t) {
        const int ms = __builtin_amdgcn_readlane(mv, t);   // SGPR, uniform
        const uint2 av = TAs[((size_t)t*16 + ms)*64 + lane];
        union { uint4 u; s16x8 v; } ua, ub;
        ua.u = make_uint4(av.x, av.y, av.x, av.y);   // duplicated K-half
        ub.u = make_uint4(h01, h23, l01, l23);
        d = __builtin_amdgcn_mfma_f32_16x16x32_bf16(ua.v, ub.v, zero, 0, 0, 0);
        asm("v_cvt_pk_bf16_f32 %0, %1, %2" : "=v"(h01) : "v"(d[0]), "v"(d[1]));
        asm("v_cvt_pk_bf16_f32 %0, %1, %2" : "=v"(h23) : "v"(d[2]), "v"(d[3]));
        const float r0 = d[0] - __uint_as_float(h01 << 16);
        const float r1 = d[1] - __uint_as_float(h01 & 0xFFFF0000u);
        const float r2 = d[2] - __uint_as_float(h23 << 16);
        const float r3 = d[3] - __uint_as_float(h23 & 0xFFFF0000u);
        asm("v_cvt_pk_bf16_f32 %0, %1, %2" : "=v"(l01) : "v"(r0), "v"(r1));
        asm("v_cvt_pk_bf16_f32 %0, %1, %2" : "=v"(l23) : "v"(r2), "v"(r3));
    }
    #pragma unroll
    for (int j = 0; j < 4; ++j) mats[s*SLOT20 + (4*g+j)*RST + c] = d[j];
    __syncthreads();

    if (tt < 256) mulRST(mats, 2*s + 1, 2*s, 8 + s, lane);     // L0
    __syncthreads();
    if (tt < 128) mulRST(mats, 8 + 2*s + 1, 8 + 2*s, s, lane); // L1
    __syncthreads();
    if (tt < 64)  mulRST(mats, 1, 0, 2, lane);                 // L2
    __syncthreads();

    if (tt < 16) {
        float dg = mats[2*SLOT20 + tt*RST + tt];   // diag (tt,tt)
        #pragma unroll
        for (int off = 8; off >= 1; off >>= 1) dg += __shfl_xor(dg, off, 16);
        if (tt == 0) out[b] = logf(dg);
    }
}

// ---------------------------------------------------------------------------
// Merged cooperative kernel: 1024 blocks x 512 threads (exact co-residency;
// launch_bounds(512,8) caps VGPR at 64). Phase A: block bid builds
// build-block bid. Grid sync. Phase B: block bid = batch bid.
// ---------------------------------------------------------------------------
__global__ __launch_bounds__(512, 8) void mps_all(const float* __restrict__ km,
                                                  const int* __restrict__ x,
                                                  uint2* __restrict__ TA,
                                                  float* __restrict__ out) {
    __shared__ float L[13 * SLOT20];
    const int tt  = threadIdx.x;
    const int bid = blockIdx.x;
    build_phase(L, km, TA, bid, tt);
    __threadfence();
    cg::this_grid().sync();
    chain_phase(L, TA, x, out, bid, tt);
}

// ---------------------------------------------------------------------------
// Fallback path: verified R11 two-kernel pipeline (22.8 us).
// ---------------------------------------------------------------------------
__global__ __launch_bounds__(256) void build_frag3(const float* __restrict__ km,
                                                   uint2* __restrict__ TA) {
    __shared__ float L[13 * SLOT20];
    build_phase(L, km, TA, blockIdx.x, threadIdx.x);
}

__global__ __launch_bounds__(512) void mps_fused(const uint2* __restrict__ TA,
                                                 const int* __restrict__ x,
                                                 float* __restrict__ out) {
    __shared__ float mats[12 * SLOT20];
    chain_phase(mats, TA, x, out, blockIdx.x, threadIdx.x);
}

// ---------------------------------------------------------------------------
// Fallback (tiny ws): verified R1 raw-chain fp32 path.
// ---------------------------------------------------------------------------
__global__ void seg_prod1(const float* __restrict__ T, const int* __restrict__ x,
                          float* __restrict__ P, const int S, const int lgS) {
    const int tid  = blockIdx.x * blockDim.x + threadIdx.x;
    const int j    = tid & 15;
    const int item = tid >> 4;
    if (item >= BB * S) return;
    const int s = item & (S - 1);
    const int b = item >> lgS;
    float c[16];
    #pragma unroll
    for (int q = 0; q < 16; ++q) c[q] = (q == j) ? 1.f : 0.f;
    const int nsteps = LL / S;
    const int base   = s * nsteps;
    for (int cc = 0; cc < nsteps; ++cc) {
        const int l = base + cc;
        const int xv = x[(size_t)b*LL + l];
        const float4* Mrow = reinterpret_cast<const float4*>(T + ((size_t)l*2 + xv)*256);
        float4 n0 = make_float4(0.f,0.f,0.f,0.f), n1 = n0, n2 = n0, n3 = n0;
        #pragma unroll
        for (int i = 0; i < 16; ++i) {
            const float a = c[i];
            const float4 r0 = Mrow[i*4+0], r1 = Mrow[i*4+1], r2 = Mrow[i*4+2], r3 = Mrow[i*4+3];
            FMA4(n0, a, r0); FMA4(n1, a, r1); FMA4(n2, a, r2); FMA4(n3, a, r3);
        }
        c[0]=n0.x; c[1]=n0.y; c[2]=n0.z; c[3]=n0.w;
        c[4]=n1.x; c[5]=n1.y; c[6]=n1.z; c[7]=n1.w;
        c[8]=n2.x; c[9]=n2.y; c[10]=n2.z; c[11]=n2.w;
        c[12]=n3.x; c[13]=n3.y; c[14]=n3.z; c[15]=n3.w;
    }
    float4* Pp = reinterpret_cast<float4*>(P + (size_t)item*256 + j*16);
    Pp[0] = make_float4(c[0],c[1],c[2],c[3]);
    Pp[1] = make_float4(c[4],c[5],c[6],c[7]);
    Pp[2] = make_float4(c[8],c[9],c[10],c[11]);
    Pp[3] = make_float4(c[12],c[13],c[14],c[15]);
}

__global__ void combine_gen(const float* __restrict__ P, float* __restrict__ out,
                            const int S) {
    const int g = threadIdx.x >> 4;
    const int j = threadIdx.x & 15;
    const int b = blockIdx.x * 4 + g;
    float c[16];
    {
        const float4* p0 = reinterpret_cast<const float4*>(P + (size_t)(b*S)*256 + j*16);
        const float4 v0 = p0[0], v1 = p0[1], v2 = p0[2], v3 = p0[3];
        c[0]=v0.x; c[1]=v0.y; c[2]=v0.z; c[3]=v0.w;
        c[4]=v1.x; c[5]=v1.y; c[6]=v1.z; c[7]=v1.w;
        c[8]=v2.x; c[9]=v2.y; c[10]=v2.z; c[11]=v2.w;
        c[12]=v3.x; c[13]=v3.y; c[14]=v3.z; c[15]=v3.w;
    }
    for (int s = 1; s < S; ++s) {
        const float4* Mrow = reinterpret_cast<const float4*>(P + (size_t)(b*S + s)*256);
        float4 n0 = make_float4(0.f,0.f,0.f,0.f), n1 = n0, n2 = n0, n3 = n0;
        #pragma unroll
        for (int i = 0; i < 16; ++i) {
            const float a = c[i];
            const float4 r0 = Mrow[i*4+0], r1 = Mrow[i*4+1], r2 = Mrow[i*4+2], r3 = Mrow[i*4+3];
            FMA4(n0, a, r0); FMA4(n1, a, r1); FMA4(n2, a, r2); FMA4(n3, a, r3);
        }
        c[0]=n0.x; c[1]=n0.y; c[2]=n0.z; c[3]=n0.w;
        c[4]=n1.x; c[5]=n1.y; c[6]=n1.z; c[7]=n1.w;
        c[8]=n2.x; c[9]=n2.y; c[10]=n2.z; c[11]=n2.w;
        c[12]=n3.x; c[13]=n3.y; c[14]=n3.z; c[15]=n3.w;
    }
    float diag = 0.f;
    #pragma unroll
    for (int k = 0; k < 16; ++k) diag = (k == j) ? c[k] : diag;
    #pragma unroll
    for (int off = 8; off >= 1; off >>= 1) diag += __shfl_xor(diag, off, 16);
    if (j == 0) out[b] = logf(diag);
}

// ---------------------------------------------------------------------------
extern "C" void kernel_launch(void* const* d_in, const int* in_sizes, int n_in,
                              void* d_out, int out_size, void* d_ws, size_t ws_size,
                              hipStream_t stream) {
    const int*   x  = (const int*)d_in[0];    // (B, L) int32
    const float* km = (const float*)d_in[1];  // (L, PHYS, D, D) fp32
    float* out = (float*)d_out;               // (B,) fp32

    const size_t tab = (size_t)NCHUNK4 * 16 * 64 * sizeof(uint2);    // 2 MiB

    if (ws_size >= tab) {
        uint2* TA = (uint2*)d_ws;
        // Host-side co-residency check (pure query, deterministic).
        int nb = 0;
        hipError_t qe = hipOccupancyMaxActiveBlocksPerMultiprocessor(
            &nb, (const void*)mps_all, 512, 0);
        if (qe == hipSuccess && nb >= 4) {
            void* args[] = { (void*)&km, (void*)&x, (void*)&TA, (void*)&out };
            hipLaunchCooperativeKernel((const void*)mps_all, dim3(BB), dim3(512),
                                       args, 0, stream);
        } else {
            build_frag3<<<NCHUNK4*4, 256, 0, stream>>>(km, TA);
            mps_fused<<<BB, 512, 0, stream>>>(TA, x, out);
        }
    } else {
        int S = 16;
        while (S > 1 && (size_t)BB * S * 256 * sizeof(float) > ws_size) S >>= 1;
        int lgS = 0; for (int t = S; t > 1; t >>= 1) ++lgS;
        float* P = (float*)d_ws;
        const int blocks = (BB*S*16 + 255) / 256;
        seg_prod1<<<blocks, 256, 0, stream>>>(km, x, P, S, lgS);
        combine_gen<<<BB/4, 64, 0, stream>>>(P, out, S);
    }
}

// Round 13
// 22.809 us; speedup vs baseline: 1.2544x; 1.2544x over previous
//
#include <hip/hip_runtime.h>
#include <math.h>

#define LL 1024
#define BB 1024
#define NCHUNK4 256
#define SEGS 8
#define STEPS 32           // chunk4 steps per segment
#define RST 20             // LDS row stride (floats): 2-way banks, f4-aligned
#define SLOT20 328         // LDS matrix slot stride (floats)

typedef float f32x4 __attribute__((ext_vector_type(4)));
typedef short s16x8 __attribute__((ext_vector_type(8)));

#define FMA4(acc, s, v) { (acc).x += (s)*(v).x; (acc).y += (s)*(v).y; \
                          (acc).z += (s)*(v).z; (acc).w += (s)*(v).w; }

__device__ inline unsigned f2bf(float f) {   // RNE f32->bf16 bits
    unsigned u = __float_as_uint(f);
    return (u + 0x7FFFu + ((u >> 16) & 1u)) >> 16;
}

// ---------------------------------------------------------------------------
// 16x16 fp32 matmul in stride-20 LDS, 64 threads per product (verified R10).
// sub = (q=sub>>4, j=sub&15): out[j][4q..4q+3] = sum_i X[j][i]*Y[i][4q..].
// ---------------------------------------------------------------------------
__device__ inline void mulRST(float* L, int sx, int sy, int sd, int sub) {
    const int q = sub >> 4, j = sub & 15;
    const float* X = &L[sx*SLOT20 + j*RST];
    const float* Y = &L[sy*SLOT20 + 4*q];
    float4 o = make_float4(0.f, 0.f, 0.f, 0.f);
    #pragma unroll
    for (int i = 0; i < 16; ++i) {
        const float a = X[i];
        const float4 y = *reinterpret_cast<const float4*>(Y + i*RST);
        FMA4(o, a, y);
    }
    *reinterpret_cast<float4*>(&L[sd*SLOT20 + j*RST + 4*q]) = o;
}

// ---------------------------------------------------------------------------
// Kernel 1 (verified R10): block = (chunk c, m01); wave-DAG builds the four
// (xs2,xs3) chunk products, emits deduped bf16 A-fragments of M^T.
// ---------------------------------------------------------------------------
__global__ __launch_bounds__(256) void build_frag3(const float* __restrict__ km,
                                                   uint2* __restrict__ TA) {
    const int blk = blockIdx.x;       // c*4 + m01
    const int c   = blk >> 2;
    const int m01 = blk & 3;
    const int xs0 = m01 >> 1, xs1 = m01 & 1;
    const int t = threadIdx.x;
    // slots: 0=M0 1=M1 2=M2a 3=M2b 4=M3a 5=M3b 6=P 7=Q0 8=Q1 9..12=T0..T3
    __shared__ float L[13 * SLOT20];

    const int dst = (t >> 4)*RST + (t & 15);
    L[0*SLOT20 + dst] = km[((4*c + 0)*2 + xs0)*256 + t];
    L[1*SLOT20 + dst] = km[((4*c + 1)*2 + xs1)*256 + t];
    L[2*SLOT20 + dst] = km[((4*c + 2)*2 + 0)*256 + t];
    L[3*SLOT20 + dst] = km[((4*c + 2)*2 + 1)*256 + t];
    L[4*SLOT20 + dst] = km[((4*c + 3)*2 + 0)*256 + t];
    L[5*SLOT20 + dst] = km[((4*c + 3)*2 + 1)*256 + t];
    __syncthreads();

    const int w = t >> 6, sub = t & 63;
    if (w == 0) mulRST(L, 0, 1, 6, sub);                 // P = M0@M1
    __syncthreads();
    if (w < 2) mulRST(L, 6, 2 + w, 7 + w, sub);          // Qw = P@M2[w]
    __syncthreads();
    mulRST(L, 7 + (w >> 1), 4 + (w & 1), 9 + w, sub);    // Tw = Q[w>>1]@M3[w&1]
    __syncthreads();

    {   // emit: combo qq = w, lane = sub
        const int g = sub >> 4, col = sub & 15;
        const float* Tq = &L[(9 + w) * SLOT20];
        const unsigned a0 = f2bf(Tq[(4*g+0)*RST + col]);
        const unsigned a1 = f2bf(Tq[(4*g+1)*RST + col]);
        const unsigned a2 = f2bf(Tq[(4*g+2)*RST + col]);
        const unsigned a3 = f2bf(Tq[(4*g+3)*RST + col]);
        TA[((size_t)c*16 + m01*4 + w)*64 + sub] =
            make_uint2(a0 | (a1 << 16), a2 | (a3 << 16));
    }
}

// ---------------------------------------------------------------------------
// Kernel 2 (verified R11): fused chains + combine. Chain MFMA/cvt math
// identical to R7-R11 (bit-identical output). Scalarized step indices:
// lanes 0..31 precompute the 32 m-values (one coalesced int4 load each),
// the unrolled loop lifts m to SGPR via readlane, so the table address is
// SGPR-base + fixed per-lane offset (ideal saddr+voffset form; SALU ∥ VALU).
// ---------------------------------------------------------------------------
__global__ __launch_bounds__(512) void mps_fused(const uint2* __restrict__ TA,
                                                 const int* __restrict__ x,
                                                 float* __restrict__ out) {
    __shared__ float mats[12 * SLOT20];
    const int tt   = threadIdx.x;
    const int b    = blockIdx.x;
    const int s    = tt >> 6;          // wave = segment
    const int lane = tt & 63;
    const int g = lane >> 4, c = lane & 15;

    // lanes 0..31: m-value for step `lane` of this wave's segment
    int mv = 0;
    {
        const int4* xp4 = reinterpret_cast<const int4*>(x + (size_t)b*LL + s*(STEPS*4));
        if (lane < STEPS) {
            const int4 xv = xp4[lane];
            mv = (xv.x<<3) | (xv.y<<2) | (xv.z<<1) | xv.w;
        }
    }
    const uint2* __restrict__ TAs = TA + (size_t)s*STEPS*16*64;

    const f32x4 zero = {0.f, 0.f, 0.f, 0.f};
    f32x4 d = zero;
    unsigned h01 = ((4*g+0==c)?0x3F80u:0u) | (((4*g+1==c)?0x3F80u:0u) << 16);
    unsigned h23 = ((4*g+2==c)?0x3F80u:0u) | (((4*g+3==c)?0x3F80u:0u) << 16);
    unsigned l01 = 0u, l23 = 0u;

    #pragma unroll
    for (int t = 0; t < STEPS; ++t) {
        const int ms = __builtin_amdgcn_readlane(mv, t);   // SGPR, uniform
        const uint2 av = TAs[((size_t)t*16 + ms)*64 + lane];
        union { uint4 u; s16x8 v; } ua, ub;
        ua.u = make_uint4(av.x, av.y, av.x, av.y);   // duplicated K-half
        ub.u = make_uint4(h01, h23, l01, l23);
        d = __builtin_amdgcn_mfma_f32_16x16x32_bf16(ua.v, ub.v, zero, 0, 0, 0);
        asm("v_cvt_pk_bf16_f32 %0, %1, %2" : "=v"(h01) : "v"(d[0]), "v"(d[1]));
        asm("v_cvt_pk_bf16_f32 %0, %1, %2" : "=v"(h23) : "v"(d[2]), "v"(d[3]));
        const float r0 = d[0] - __uint_as_float(h01 << 16);
        const float r1 = d[1] - __uint_as_float(h01 & 0xFFFF0000u);
        const float r2 = d[2] - __uint_as_float(h23 << 16);
        const float r3 = d[3] - __uint_as_float(h23 & 0xFFFF0000u);
        asm("v_cvt_pk_bf16_f32 %0, %1, %2" : "=v"(l01) : "v"(r0), "v"(r1));
        asm("v_cvt_pk_bf16_f32 %0, %1, %2" : "=v"(l23) : "v"(r2), "v"(r3));
    }
    // R_s into LDS slot s: d[j] = R_s[4g+j][c]
    #pragma unroll
    for (int j = 0; j < 4; ++j) mats[s*SLOT20 + (4*g+j)*RST + c] = d[j];
    __syncthreads();

    // L0 (waves 0..3): slot(8+p) = R_{2p+1} @ R_{2p}
    if (tt < 256) mulRST(mats, 2*s + 1, 2*s, 8 + s, lane);
    __syncthreads();
    // L1 (waves 0..1): slot(p) = slot(8+2p+1) @ slot(8+2p)
    if (tt < 128) mulRST(mats, 8 + 2*s + 1, 8 + 2*s, s, lane);
    __syncthreads();
    // L2 (wave 0): slot(2) = slot(1) @ slot(0)
    if (tt < 64) mulRST(mats, 1, 0, 2, lane);
    __syncthreads();

    if (tt < 16) {
        float dg = mats[2*SLOT20 + tt*RST + tt];   // diag (tt,tt)
        #pragma unroll
        for (int off = 8; off >= 1; off >>= 1) dg += __shfl_xor(dg, off, 16);
        if (tt == 0) out[b] = logf(dg);
    }
}

// ---------------------------------------------------------------------------
// Fallback (tiny ws): verified R1 raw-chain fp32 path.
// ---------------------------------------------------------------------------
__global__ void seg_prod1(const float* __restrict__ T, const int* __restrict__ x,
                          float* __restrict__ P, const int S, const int lgS) {
    const int tid  = blockIdx.x * blockDim.x + threadIdx.x;
    const int j    = tid & 15;
    const int item = tid >> 4;
    if (item >= BB * S) return;
    const int s = item & (S - 1);
    const int b = item >> lgS;
    float c[16];
    #pragma unroll
    for (int q = 0; q < 16; ++q) c[q] = (q == j) ? 1.f : 0.f;
    const int nsteps = LL / S;
    const int base   = s * nsteps;
    for (int cc = 0; cc < nsteps; ++cc) {
        const int l = base + cc;
        const int xv = x[(size_t)b*LL + l];
        const float4* Mrow = reinterpret_cast<const float4*>(T + ((size_t)l*2 + xv)*256);
        float4 n0 = make_float4(0.f,0.f,0.f,0.f), n1 = n0, n2 = n0, n3 = n0;
        #pragma unroll
        for (int i = 0; i < 16; ++i) {
            const float a = c[i];
            const float4 r0 = Mrow[i*4+0], r1 = Mrow[i*4+1], r2 = Mrow[i*4+2], r3 = Mrow[i*4+3];
            FMA4(n0, a, r0); FMA4(n1, a, r1); FMA4(n2, a, r2); FMA4(n3, a, r3);
        }
        c[0]=n0.x; c[1]=n0.y; c[2]=n0.z; c[3]=n0.w;
        c[4]=n1.x; c[5]=n1.y; c[6]=n1.z; c[7]=n1.w;
        c[8]=n2.x; c[9]=n2.y; c[10]=n2.z; c[11]=n2.w;
        c[12]=n3.x; c[13]=n3.y; c[14]=n3.z; c[15]=n3.w;
    }
    float4* Pp = reinterpret_cast<float4*>(P + (size_t)item*256 + j*16);
    Pp[0] = make_float4(c[0],c[1],c[2],c[3]);
    Pp[1] = make_float4(c[4],c[5],c[6],c[7]);
    Pp[2] = make_float4(c[8],c[9],c[10],c[11]);
    Pp[3] = make_float4(c[12],c[13],c[14],c[15]);
}

__global__ void combine_gen(const float* __restrict__ P, float* __restrict__ out,
                            const int S) {
    const int g = threadIdx.x >> 4;
    const int j = threadIdx.x & 15;
    const int b = blockIdx.x * 4 + g;
    float c[16];
    {
        const float4* p0 = reinterpret_cast<const float4*>(P + (size_t)(b*S)*256 + j*16);
        const float4 v0 = p0[0], v1 = p0[1], v2 = p0[2], v3 = p0[3];
        c[0]=v0.x; c[1]=v0.y; c[2]=v0.z; c[3]=v0.w;
        c[4]=v1.x; c[5]=v1.y; c[6]=v1.z; c[7]=v1.w;
        c[8]=v2.x; c[9]=v2.y; c[10]=v2.z; c[11]=v2.w;
        c[12]=v3.x; c[13]=v3.y; c[14]=v3.z; c[15]=v3.w;
    }
    for (int s = 1; s < S; ++s) {
        const float4* Mrow = reinterpret_cast<const float4*>(P + (size_t)(b*S + s)*256);
        float4 n0 = make_float4(0.f,0.f,0.f,0.f), n1 = n0, n2 = n0, n3 = n0;
        #pragma unroll
        for (int i = 0; i < 16; ++i) {
            const float a = c[i];
            const float4 r0 = Mrow[i*4+0], r1 = Mrow[i*4+1], r2 = Mrow[i*4+2], r3 = Mrow[i*4+3];
            FMA4(n0, a, r0); FMA4(n1, a, r1); FMA4(n2, a, r2); FMA4(n3, a, r3);
        }
        c[0]=n0.x; c[1]=n0.y; c[2]=n0.z; c[3]=n0.w;
        c[4]=n1.x; c[5]=n1.y; c[6]=n1.z; c[7]=n1.w;
        c[8]=n2.x; c[9]=n2.y; c[10]=n2.z; c[11]=n2.w;
        c[12]=n3.x; c[13]=n3.y; c[14]=n3.z; c[15]=n3.w;
    }
    float diag = 0.f;
    #pragma unroll
    for (int k = 0; k < 16; ++k) diag = (k == j) ? c[k] : diag;
    #pragma unroll
    for (int off = 8; off >= 1; off >>= 1) diag += __shfl_xor(diag, off, 16);
    if (j == 0) out[b] = logf(diag);
}

// ---------------------------------------------------------------------------
extern "C" void kernel_launch(void* const* d_in, const int* in_sizes, int n_in,
                              void* d_out, int out_size, void* d_ws, size_t ws_size,
                              hipStream_t stream) {
    const int*   x  = (const int*)d_in[0];    // (B, L) int32
    const float* km = (const float*)d_in[1];  // (L, PHYS, D, D) fp32
    float* out = (float*)d_out;               // (B,) fp32

    const size_t tab = (size_t)NCHUNK4 * 16 * 64 * sizeof(uint2);    // 2 MiB

    if (ws_size >= tab) {
        uint2* TA = (uint2*)d_ws;
        build_frag3<<<NCHUNK4*4, 256, 0, stream>>>(km, TA);
        mps_fused<<<BB, 512, 0, stream>>>(TA, x, out);
    } else {
        int S = 16;
        while (S > 1 && (size_t)BB * S * 256 * sizeof(float) > ws_size) S >>= 1;
        int lgS = 0; for (int t = S; t > 1; t >>= 1) ++lgS;
        float* P = (float*)d_ws;
        const int blocks = (BB*S*16 + 255) / 256;
        seg_prod1<<<blocks, 256, 0, stream>>>(km, x, P, S, lgS);
        combine_gen<<<BB/4, 64, 0, stream>>>(P, out, S);
    }
}